// Round 6
// baseline (182.525 us; speedup 1.0000x reference)
//
#include <hip/hip_runtime.h>
#include <hip/hip_bf16.h>
#include <stdint.h>

// out = tril(Q K^T) * scale @ V  (no softmax), Q/K/V = x @ W^T + b
// B=4, N=2048, D=1024, f32 in/out; bf16 MFMA, f32 accum.
// QKV: 256x256 BK=64 8-phase (pair-restructured, B-frag reuse).
// scores: 128x256 BK=64 2-phase/K-tile, 288 equal blocks.
// PV: 128x128 m97-style kernel.

typedef __attribute__((ext_vector_type(4))) float f32x4;
typedef __attribute__((ext_vector_type(8))) short bf16x8s;
typedef __attribute__((ext_vector_type(4))) short bf16x4s;

__device__ __forceinline__ short f2bf(float f) {
  union { float f; unsigned u; } v; v.f = f;
  return (short)((v.u + 0x7FFFu + ((v.u >> 16) & 1u)) >> 16);  // RNE
}

// ---------------- fused cast f32 -> bf16 ----------------
__global__ void cast_all(const float* __restrict__ x, const float* __restrict__ wq,
                         const float* __restrict__ wk, const float* __restrict__ wv,
                         short* __restrict__ xb, short* __restrict__ wcat) {
  const int n4x = 1 << 21;
  const int n4w = 1 << 18;
  const int total = n4x + 3 * n4w;
  int idx = blockIdx.x * blockDim.x + threadIdx.x;
  int stride = gridDim.x * blockDim.x;
  for (int i = idx; i < total; i += stride) {
    f32x4 v;
    short* dst;
    if (i < n4x) {
      v = ((const f32x4*)x)[i];
      dst = xb + (size_t)i * 4;
    } else {
      int j = i - n4x;
      int sel = j >> 18, off = j & (n4w - 1);
      const float* src = (sel == 0) ? wq : (sel == 1) ? wk : wv;
      v = ((const f32x4*)src)[off];
      dst = wcat + (size_t)j * 4;
    }
    bf16x4s o;
    o[0] = f2bf(v[0]); o[1] = f2bf(v[1]); o[2] = f2bf(v[2]); o[3] = f2bf(v[3]);
    *(bf16x4s*)dst = o;
  }
}

// ---------------- shared staging / fragment-read machinery ----------------
// Swizzle: 16B-slot s = ks ^ ((row>>1)&3); inverse on global src, applied on ds_read.

// stage a 256-row x 32-col half (16KB): 2 gload_lds(16B)/thread, linear LDS dest
#define STAGE(gp, ld_, kelem, slot)                                                   \
  {                                                                                   \
    const int ksrc_ = (((lane & 3) ^ ((lane >> 3) & 3)) << 3);                        \
    _Pragma("unroll") for (int e_ = 0; e_ < 2; ++e_) {                                \
      int row_ = e_ * 128 + wid * 16 + (lane >> 2);                                   \
      const short* src_ = (gp) + (size_t)row_ * (ld_) + (kelem) + ksrc_;              \
      __builtin_amdgcn_global_load_lds(                                               \
          (const __attribute__((address_space(1))) void*)src_,                        \
          (__attribute__((address_space(3))) void*)((slot) + e_ * 4096 + wid * 512),  \
          16, 0, 0);                                                                  \
    }                                                                                 \
  }

// stage a 128-row x 32-col half (8KB): 1 gload_lds(16B)/thread
#define STAGE1(gp, ld_, kelem, slot)                                                  \
  {                                                                                   \
    const int ksrc_ = (((lane & 3) ^ ((lane >> 3) & 3)) << 3);                        \
    int row_ = wid * 16 + (lane >> 2);                                                \
    const short* src_ = (gp) + (size_t)row_ * (ld_) + (kelem) + ksrc_;                \
    __builtin_amdgcn_global_load_lds(                                                 \
        (const __attribute__((address_space(1))) void*)src_,                          \
        (__attribute__((address_space(3))) void*)((slot) + wid * 512), 16, 0, 0);     \
  }

#define LDSF(slot, row) \
  (*(const bf16x8s*)&(slot)[(row) * 32 + ((kq ^ (((row) >> 1) & 3)) << 3)])

// =================== QKV: 256x256, 8 waves (2x4), pair phases ===================
#define MFMA16(ch)                                                                     \
  _Pragma("unroll") for (int mi_ = 0; mi_ < 4; ++mi_)                                  \
  _Pragma("unroll") for (int nj_ = 0; nj_ < 4; ++nj_)                                  \
    acc[(ch) * 4 + mi_][nj_] = __builtin_amdgcn_mfma_f32_16x16x32_bf16(                \
        a_[mi_], b_[nj_], acc[(ch) * 4 + mi_][nj_], 0, 0, 0);

// pair: B-frags read ONCE, reused across both c-halves; stage/VMW schedule
// identical to the validated 4-phase version.
#define PHASEPAIR(sA_, sB_, STG0, STG1, VMC1)                          \
  {                                                                    \
    bf16x8s b_[4], a_[4];                                              \
    _Pragma("unroll") for (int nj_ = 0; nj_ < 4; ++nj_)                \
      b_[nj_] = LDSF(sB_, wn * 64 + nj_ * 16 + r16);                   \
    _Pragma("unroll") for (int mi_ = 0; mi_ < 4; ++mi_)                \
      a_[mi_] = LDSF(sA_, wm * 128 + mi_ * 16 + r16);                  \
    STG0;                                                              \
    __builtin_amdgcn_s_barrier();                                      \
    asm volatile("s_waitcnt lgkmcnt(0)" ::: "memory");                 \
    __builtin_amdgcn_s_setprio(1);                                     \
    MFMA16(0)                                                          \
    __builtin_amdgcn_s_setprio(0);                                     \
    __builtin_amdgcn_s_barrier();                                      \
    _Pragma("unroll") for (int mi_ = 0; mi_ < 4; ++mi_)                \
      a_[mi_] = LDSF(sA_, wm * 128 + 64 + mi_ * 16 + r16);             \
    STG1;                                                              \
    __builtin_amdgcn_s_barrier();                                      \
    asm volatile("s_waitcnt lgkmcnt(0)" ::: "memory");                 \
    __builtin_amdgcn_s_setprio(1);                                     \
    MFMA16(1)                                                          \
    __builtin_amdgcn_s_setprio(0);                                     \
    VMC1;                                                              \
    __builtin_amdgcn_s_barrier();                                      \
  }

#define VMW8 asm volatile("s_waitcnt vmcnt(8)" ::: "memory")

__global__ __launch_bounds__(512, 1) void gemm_qkv(
    const short* __restrict__ A, const short* __restrict__ Bm,
    const float* __restrict__ bq, const float* __restrict__ bk,
    const float* __restrict__ bv, short* __restrict__ Qb,
    short* __restrict__ Kb, short* __restrict__ Vt) {
  const int NT = 16;
  int id = blockIdx.x;                       // 384 blocks, XCD-bijective swizzle
  int swz = (id & 7) * 48 + (id >> 3);
  const int tx = swz % 12, ty = swz / 12;
  const short* Ap = A + (size_t)(ty * 256) * 1024;
  const short* Bp = Bm + (size_t)(tx * 256) * 1024;

  __shared__ short lds[8][8192];  // 128 KiB

  const int tid = threadIdx.x;
  const int wid = tid >> 6, lane = tid & 63;
  const int wm = wid >> 2, wn = wid & 3;     // 2 x 4 waves, each 128x64 output
  const int kq = lane >> 4, r16 = lane & 15;

  f32x4 acc[8][4];
#pragma unroll
  for (int i = 0; i < 8; ++i)
#pragma unroll
    for (int j = 0; j < 4; ++j) { f32x4 z = {0.f, 0.f, 0.f, 0.f}; acc[i][j] = z; }

  // prologue: A_k0(0),B_k0(0),A_k1(0),B_k1(0),A_k0(1),B_k0(1)
  STAGE(Ap, 1024, 0,  (&lds[0][0]));
  STAGE(Bp, 1024, 0,  (&lds[4][0]));
  STAGE(Ap, 1024, 32, (&lds[2][0]));
  STAGE(Bp, 1024, 32, (&lds[6][0]));
  STAGE(Ap, 1024, 64, (&lds[1][0]));
  STAGE(Bp, 1024, 64, (&lds[5][0]));
  VMW8;  // 12 issued -> A_k0(0), B_k0(0) landed
  __builtin_amdgcn_s_barrier();

  for (int T = 0; T < NT; ++T) {
    const int par = T & 1;
    short* sA0 = &lds[0 + par][0];
    short* sA1 = &lds[2 + par][0];
    short* sB0 = &lds[4 + par][0];
    short* sB1 = &lds[6 + par][0];
    short* sA1n = &lds[2 + (par ^ 1)][0];
    short* sB1n = &lds[6 + (par ^ 1)][0];
    const int kN1 = min(T + 1, NT - 1) * 64 + 32;
    const int kN2 = min(T + 2, NT - 1) * 64;
    // pair0: k-half0 (c0 then c1); stage A_k1(T+1), B_k1(T+1)
    PHASEPAIR(sA0, sB0, STAGE(Ap, 1024, kN1, sA1n), STAGE(Bp, 1024, kN1, sB1n), VMW8);
    // pair1: k-half1; stage A_k0(T+2), B_k0(T+2)
    PHASEPAIR(sA1, sB1, STAGE(Ap, 1024, kN2, sA0), STAGE(Bp, 1024, kN2, sB0), VMW8);
  }

  // epilogue
  const int rowt0 = ty * 256 + wm * 128;
  const int seg = tx >> 2;                       // 0:Q 1:K 2:V
  const int colseg0 = (tx & 3) * 256 + wn * 64;
  if (seg < 2) {
    short* Cb = (seg == 0) ? Qb : Kb;
    const float* bias = (seg == 0) ? bq : bk;
#pragma unroll
    for (int mf = 0; mf < 8; ++mf) {
#pragma unroll
      for (int nj = 0; nj < 4; ++nj) {
        int col = colseg0 + nj * 16 + r16;
        float bvv = bias[col];
#pragma unroll
        for (int rr = 0; rr < 4; ++rr) {
          int row = rowt0 + mf * 16 + kq * 4 + rr;
          Cb[(size_t)row * 1024 + col] = f2bf(acc[mf][nj][rr] + bvv);
        }
      }
    }
  } else {
#pragma unroll
    for (int mf = 0; mf < 8; ++mf) {
      int rowg = rowt0 + mf * 16 + kq * 4;
      int b = rowg >> 11, n0 = rowg & 2047;
      long long base = (long long)b * (1024LL * 2048LL);
#pragma unroll
      for (int nj = 0; nj < 4; ++nj) {
        int col = colseg0 + nj * 16 + r16;
        float bvv = bv[col];
        bf16x4s o;
#pragma unroll
        for (int rr = 0; rr < 4; ++rr) o[rr] = f2bf(acc[mf][nj][rr] + bvv);
        *(bf16x4s*)&Vt[base + (long long)col * 2048 + n0] = o;
      }
    }
  }
}

// =================== scores: 128q x 256k, 2 phases/K-tile ===================
#define VMW6 asm volatile("s_waitcnt vmcnt(6)" ::: "memory")

#define SCPHASE(sA_, sB_, STG)                                         \
  {                                                                    \
    bf16x8s a_[4], b_[4];                                              \
    _Pragma("unroll") for (int mi_ = 0; mi_ < 4; ++mi_)                \
      a_[mi_] = LDSF(sA_, wm * 64 + mi_ * 16 + r16);                   \
    _Pragma("unroll") for (int nj_ = 0; nj_ < 4; ++nj_)                \
      b_[nj_] = LDSF(sB_, wn * 64 + nj_ * 16 + r16);                   \
    STG;                                                               \
    __builtin_amdgcn_s_barrier();                                      \
    asm volatile("s_waitcnt lgkmcnt(0)" ::: "memory");                 \
    __builtin_amdgcn_s_setprio(1);                                     \
    _Pragma("unroll") for (int mi_ = 0; mi_ < 4; ++mi_)                \
    _Pragma("unroll") for (int nj_ = 0; nj_ < 4; ++nj_)                \
      acc[mi_][nj_] = __builtin_amdgcn_mfma_f32_16x16x32_bf16(         \
          a_[mi_], b_[nj_], acc[mi_][nj_], 0, 0, 0);                   \
    __builtin_amdgcn_s_setprio(0);                                     \
    VMW6;                                                              \
    __builtin_amdgcn_s_barrier();                                      \
  }

__global__ __launch_bounds__(512, 1) void gemm_sc(
    const short* __restrict__ Q, const short* __restrict__ K,
    short* __restrict__ S, float scale) {
  const int NT = 16;
  const int bz = blockIdx.z;
  int id = blockIdx.x;                 // 72 lower-tri (128q x 256k) tiles per batch
  int ti = (id & 7) * 9 + (id >> 3);   // XCD-bijective (72 = 8*9)
  int qt = 0, c = 0;
  while (c + (qt / 2 + 1) <= ti) { c += qt / 2 + 1; ++qt; }
  const int kt = ti - c;

  const short* Ap = Q + (long long)bz * (2048LL * 1024LL) + (size_t)(qt * 128) * 1024;
  const short* Bp = K + (long long)bz * (2048LL * 1024LL) + (size_t)(kt * 256) * 1024;

  __shared__ short lds[49152];  // 96 KiB: A 4x4096 shorts, B 4x8192 shorts
  short* Abuf = lds;
  short* Bbuf = lds + 16384;

  const int tid = threadIdx.x;
  const int wid = tid >> 6, lane = tid & 63;
  const int wm = wid >> 2, wn = wid & 3;   // 2 x 4 waves, each 64x64 output
  const int kq = lane >> 4, r16 = lane & 15;

  f32x4 acc[4][4];
#pragma unroll
  for (int i = 0; i < 4; ++i)
#pragma unroll
    for (int j = 0; j < 4; ++j) { f32x4 z = {0.f, 0.f, 0.f, 0.f}; acc[i][j] = z; }

  // A slots: idx = h*2+par (4KB shorts each); B slots: idx = h*2+par (8KB shorts)
  STAGE1(Ap, 1024, 0,  (Abuf + 0 * 4096));  // A_k0[0]
  STAGE (Bp, 1024, 0,  (Bbuf + 0 * 8192));  // B_k0[0]
  STAGE1(Ap, 1024, 32, (Abuf + 2 * 4096));  // A_k1[0]
  STAGE (Bp, 1024, 32, (Bbuf + 2 * 8192));  // B_k1[0]
  STAGE1(Ap, 1024, 64, (Abuf + 1 * 4096));  // A_k0[1]
  STAGE (Bp, 1024, 64, (Bbuf + 1 * 8192));  // B_k0[1]
  VMW6;  // 9 issued -> k0(0) landed
  __builtin_amdgcn_s_barrier();

  for (int T = 0; T < NT; ++T) {
    const int par = T & 1;
    const int kN1 = min(T + 1, NT - 1) * 64 + 32;
    const int kN2 = min(T + 2, NT - 1) * 64;
    // p0: k-half0; stage k1(T+1) -> slots [2 + (par^1)]
    SCPHASE((Abuf + par * 4096), (Bbuf + par * 8192),
            { STAGE1(Ap, 1024, kN1, (Abuf + (2 + (par ^ 1)) * 4096));
              STAGE (Bp, 1024, kN1, (Bbuf + (2 + (par ^ 1)) * 8192)); });
    // p1: k-half1; stage k0(T+2) -> slots [par]
    SCPHASE((Abuf + (2 + par) * 4096), (Bbuf + (2 + par) * 8192),
            { STAGE1(Ap, 1024, kN2, (Abuf + par * 4096));
              STAGE (Bp, 1024, kN2, (Bbuf + par * 8192)); });
  }

  short* Cb = S + (long long)bz * (2048LL * 2048LL);
  const int rowt0 = qt * 128 + wm * 64;
  const int colt0 = kt * 256 + wn * 64;
#pragma unroll
  for (int mf = 0; mf < 4; ++mf) {
#pragma unroll
    for (int nj = 0; nj < 4; ++nj) {
      int col = colt0 + nj * 16 + r16;
#pragma unroll
      for (int rr = 0; rr < 4; ++rr) {
        int row = rowt0 + mf * 16 + kq * 4 + rr;
        float v = (col <= row) ? acc[mf][nj][rr] * scale : 0.0f;
        Cb[(size_t)row * 2048 + col] = f2bf(v);
      }
    }
  }
}

// =================== 128x128 m97-style PV kernel ===================
#define BM 128
#define BN 128
#define BKK 32

__global__ __launch_bounds__(256) void gemm_pv(
    const short* __restrict__ S, const short* __restrict__ Vt,
    float* __restrict__ O) {
  const int tx = blockIdx.x, bz = blockIdx.z;
  const int ty = (int)gridDim.y - 1 - (int)blockIdx.y;  // longest-first
  const int Kend = (ty + 1) * BM;

  const short* Ab = S + (long long)bz * (2048LL * 2048LL);
  const short* Bb = Vt + (long long)bz * (1024LL * 2048LL);
  const int arow0 = ty * BM, brow0 = tx * BN;

  __shared__ short As[BM * BKK];
  __shared__ short Bs[BN * BKK];
  const int tid = threadIdx.x;
  const int wid = tid >> 6, lane = tid & 63;
  const int wm = wid >> 1, wn = wid & 1;
  const int kq = lane >> 4, r16 = lane & 15;
  const int srow = lane >> 2, scol = (lane & 3) * 8;
  f32x4 acc[4][4];
#pragma unroll
  for (int i = 0; i < 4; ++i)
#pragma unroll
    for (int j = 0; j < 4; ++j) { f32x4 z = {0.f, 0.f, 0.f, 0.f}; acc[i][j] = z; }

  for (int k0 = 0; k0 < Kend; k0 += BKK) {
    __syncthreads();
#pragma unroll
    for (int p = 0; p < 2; ++p) {
      int c = p * 4 + wid;
      const short* ga = Ab + ((size_t)(arow0 + c * 16 + srow)) * 2048 + k0 + scol;
      __builtin_amdgcn_global_load_lds(
          (const __attribute__((address_space(1))) void*)ga,
          (__attribute__((address_space(3))) void*)&As[c * 512], 16, 0, 0);
      const short* gb = Bb + ((size_t)(brow0 + c * 16 + srow)) * 2048 + k0 + scol;
      __builtin_amdgcn_global_load_lds(
          (const __attribute__((address_space(1))) void*)gb,
          (__attribute__((address_space(3))) void*)&Bs[c * 512], 16, 0, 0);
    }
    asm volatile("s_waitcnt vmcnt(0)" ::: "memory");
    __syncthreads();
    bf16x8s af[4], bfr[4];
#pragma unroll
    for (int i = 0; i < 4; ++i)
      af[i] = *(const bf16x8s*)&As[(wm * 64 + i * 16 + r16) * BKK + kq * 8];
#pragma unroll
    for (int j = 0; j < 4; ++j)
      bfr[j] = *(const bf16x8s*)&Bs[(wn * 64 + j * 16 + r16) * BKK + kq * 8];
#pragma unroll
    for (int i = 0; i < 4; ++i)
#pragma unroll
      for (int j = 0; j < 4; ++j)
        acc[i][j] = __builtin_amdgcn_mfma_f32_16x16x32_bf16(af[i], bfr[j], acc[i][j], 0, 0, 0);
  }

  float* Cb = O + (long long)bz * (2048LL * 1024LL);
  const int row0 = ty * BM + wm * 64;
  const int col0 = tx * BN + wn * 64;
#pragma unroll
  for (int i2 = 0; i2 < 4; ++i2) {
#pragma unroll
    for (int j = 0; j < 4; ++j) {
      int col = col0 + j * 16 + r16;
#pragma unroll
      for (int r = 0; r < 4; ++r) {
        int row = row0 + i2 * 16 + kq * 4 + r;
        Cb[(size_t)row * 1024 + col] = acc[i2][j][r];
      }
    }
  }
}

extern "C" void kernel_launch(void* const* d_in, const int* in_sizes, int n_in,
                              void* d_out, int out_size, void* d_ws, size_t ws_size,
                              hipStream_t stream) {
  const float* x  = (const float*)d_in[0];
  const float* Wq = (const float*)d_in[1];
  const float* bq = (const float*)d_in[2];
  const float* Wk = (const float*)d_in[3];
  const float* bk = (const float*)d_in[4];
  const float* Wv = (const float*)d_in[5];
  const float* bv = (const float*)d_in[6];

  const int B = 4;
  const long long MB = 1LL << 20;

  char* ws = (char*)d_ws;
  short* Qb   = (short*)(ws + 0 * MB);   // 16 MB bf16 Q [8192,1024]
  short* Kb   = (short*)(ws + 16 * MB);  // 16 MB bf16 K
  short* Vt   = (short*)(ws + 32 * MB);  // 16 MB bf16 V^T [4][1024][2048]
  short* xb   = (short*)(ws + 48 * MB);  // 16 MB bf16 x     (dead after QKV)
  short* Wcat = (short*)(ws + 64 * MB);  // 6 MB  bf16 [Wq;Wk;Wv] (dead after QKV)
  short* Sb   = (short*)(ws + 48 * MB);  // 32 MB scores, reuses xb/Wcat

  // 1. fused casts
  cast_all<<<2048, 256, 0, stream>>>(x, Wq, Wk, Wv, xb, Wcat);

  // 2. fused QKV projection: [8192,3072] = xb @ Wcat^T ; 384 blocks of 512 thr
  gemm_qkv<<<384, 512, 0, stream>>>(xb, Wcat, bq, bk, bv, Qb, Kb, Vt);

  // 3. scores: per batch S = tril(Q K^T) / 32, 72 (128x256) tiles x 4 batches
  dim3 g2(72, 1, B);
  gemm_sc<<<g2, 512, 0, stream>>>(Qb, Kb, Sb, 0.03125f);

  // 4. PV: per batch O = S @ Vt^T, causal K-extent, longest-first
  dim3 g3(8, 16, B);
  gemm_pv<<<g3, 256, 0, stream>>>(Sb, Vt, (float*)d_out);
}

// Round 8
// 170.208 us; speedup vs baseline: 1.0724x; 1.0724x over previous
//
#include <hip/hip_runtime.h>
#include <hip/hip_bf16.h>
#include <stdint.h>

// out = tril(Q K^T) * scale @ V  (no softmax), Q/K/V = x @ W^T + b
// B=4, N=2048, D=1024, f32 in/out; bf16 MFMA, f32 accum.
// QKV + scores: 128x256 tile, BK=32, 2-phase/K-tile, 48 KiB LDS, 2 blocks/CU.
// PV: 128x128 m97-style kernel.

typedef __attribute__((ext_vector_type(4))) float f32x4;
typedef __attribute__((ext_vector_type(8))) short bf16x8s;
typedef __attribute__((ext_vector_type(4))) short bf16x4s;

__device__ __forceinline__ short f2bf(float f) {
  union { float f; unsigned u; } v; v.f = f;
  return (short)((v.u + 0x7FFFu + ((v.u >> 16) & 1u)) >> 16);  // RNE
}

// ---------------- fused cast f32 -> bf16 ----------------
__global__ void cast_all(const float* __restrict__ x, const float* __restrict__ wq,
                         const float* __restrict__ wk, const float* __restrict__ wv,
                         short* __restrict__ xb, short* __restrict__ wcat) {
  const int n4x = 1 << 21;
  const int n4w = 1 << 18;
  const int total = n4x + 3 * n4w;
  int idx = blockIdx.x * blockDim.x + threadIdx.x;
  int stride = gridDim.x * blockDim.x;
  for (int i = idx; i < total; i += stride) {
    f32x4 v;
    short* dst;
    if (i < n4x) {
      v = ((const f32x4*)x)[i];
      dst = xb + (size_t)i * 4;
    } else {
      int j = i - n4x;
      int sel = j >> 18, off = j & (n4w - 1);
      const float* src = (sel == 0) ? wq : (sel == 1) ? wk : wv;
      v = ((const f32x4*)src)[off];
      dst = wcat + (size_t)j * 4;
    }
    bf16x4s o;
    o[0] = f2bf(v[0]); o[1] = f2bf(v[1]); o[2] = f2bf(v[2]); o[3] = f2bf(v[3]);
    *(bf16x4s*)dst = o;
  }
}

// ---------------- staging / fragment-read machinery ----------------
// Swizzle: 16B-slot s = ks ^ ((row>>1)&3); inverse on global src, applied on ds_read.

// stage 256 rows x 32 cols (16KB): 2 gload_lds(16B)/thread, linear LDS dest
#define STAGE2(gp, ld_, kelem, slot)                                                  \
  {                                                                                   \
    const int ksrc_ = (((lane & 3) ^ ((lane >> 3) & 3)) << 3);                        \
    _Pragma("unroll") for (int e_ = 0; e_ < 2; ++e_) {                                \
      int row_ = e_ * 128 + wid * 16 + (lane >> 2);                                   \
      const short* src_ = (gp) + (size_t)row_ * (ld_) + (kelem) + ksrc_;              \
      __builtin_amdgcn_global_load_lds(                                               \
          (const __attribute__((address_space(1))) void*)src_,                        \
          (__attribute__((address_space(3))) void*)((slot) + e_ * 4096 + wid * 512),  \
          16, 0, 0);                                                                  \
    }                                                                                 \
  }

// stage 128 rows x 32 cols (8KB): 1 gload_lds(16B)/thread
#define STAGE1(gp, ld_, kelem, slot)                                                  \
  {                                                                                   \
    const int ksrc_ = (((lane & 3) ^ ((lane >> 3) & 3)) << 3);                        \
    int row_ = wid * 16 + (lane >> 2);                                                \
    const short* src_ = (gp) + (size_t)row_ * (ld_) + (kelem) + ksrc_;                \
    __builtin_amdgcn_global_load_lds(                                                 \
        (const __attribute__((address_space(1))) void*)src_,                          \
        (__attribute__((address_space(3))) void*)((slot) + wid * 512), 16, 0, 0);     \
  }

#define LDSF(slot, row) \
  (*(const bf16x8s*)&(slot)[(row) * 32 + ((kq ^ (((row) >> 1) & 3)) << 3)])

// =================== 128x256 / BK=32 / 2-phase-per-K-tile GEMM ===================
// 512 threads = 8 waves (2m x 4n), 64x64 out/wave, acc[4][4].
// LDS: dbuf x (A 4096 + B 8192 shorts) = 48 KiB -> 2+ blocks/CU.
// Per tile: STAGE(next) -> ds_read(cur) -> lgkm -> MFMA -> vmcnt(0) -> barrier.

// MODE 0: QKV. A=xb[8192,1024], B=Wcat[3072,1024]; epilogue seg -> Qb/Kb/Vt.
// MODE 2: scores. per-batch triangular; epilogue mask+scale -> Sb.
template <int MODE>
__global__ __launch_bounds__(512, 4) void gemm2p(
    const short* __restrict__ A, const short* __restrict__ Bm,
    const float* __restrict__ bq, const float* __restrict__ bk,
    const float* __restrict__ bv, short* __restrict__ Qb,
    short* __restrict__ Kb, short* __restrict__ Vt,
    short* __restrict__ Sb, float scale) {
  const int NT = 32;  // K=1024 / BK=32
  int tx, ty;
  const short *Abase, *Bbase;
  long long bz = 0;
  if (MODE == 0) {
    int id = blockIdx.x;                 // 768 blocks; XCD-bijective (768 = 8*96)
    int swz = (id & 7) * 96 + (id >> 3);
    tx = swz % 12; ty = swz / 12;        // ty: 128-row A tile, tx: 256-row B tile
    Abase = A; Bbase = Bm;
  } else {
    bz = blockIdx.z;
    int id = blockIdx.x;                 // 72 tiles (128q x 256k); 72 = 8*9
    int ti = (id & 7) * 9 + (id >> 3);
    int qt = 0, c = 0;
    while (c + (qt / 2 + 1) <= ti) { c += qt / 2 + 1; ++qt; }
    ty = qt; tx = ti - c;
    Abase = A + bz * (2048LL * 1024LL);
    Bbase = Bm + bz * (2048LL * 1024LL);
  }
  const short* Ap = Abase + (size_t)(ty * 128) * 1024;
  const short* Bp = Bbase + (size_t)(tx * 256) * 1024;

  __shared__ short lds[24576];  // 48 KiB: A dbuf @0/4096, B dbuf @8192/16384

  const int tid = threadIdx.x;
  const int wid = tid >> 6, lane = tid & 63;
  const int wm = wid >> 2, wn = wid & 3;   // 2 x 4 waves, 64x64 out each
  const int kq = lane >> 4, r16 = lane & 15;

  f32x4 acc[4][4];
#pragma unroll
  for (int i = 0; i < 4; ++i)
#pragma unroll
    for (int j = 0; j < 4; ++j) { f32x4 z = {0.f, 0.f, 0.f, 0.f}; acc[i][j] = z; }

  // prologue
  STAGE1(Ap, 1024, 0, (lds + 0));
  STAGE2(Bp, 1024, 0, (lds + 8192));
  asm volatile("s_waitcnt vmcnt(0)" ::: "memory");
  __builtin_amdgcn_s_barrier();

  for (int T = 0; T < NT; ++T) {
    const int par = T & 1;
    short* curA = lds + par * 4096;
    short* curB = lds + 8192 + par * 8192;
    short* nxtA = lds + (par ^ 1) * 4096;
    short* nxtB = lds + 8192 + (par ^ 1) * 8192;
    if (T + 1 < NT) {
      STAGE1(Ap, 1024, (T + 1) * 32, nxtA);
      STAGE2(Bp, 1024, (T + 1) * 32, nxtB);
    }
    bf16x8s a_[4], b_[4];
#pragma unroll
    for (int mi = 0; mi < 4; ++mi)
      a_[mi] = LDSF(curA, wm * 64 + mi * 16 + r16);
#pragma unroll
    for (int nj = 0; nj < 4; ++nj)
      b_[nj] = LDSF(curB, wn * 64 + nj * 16 + r16);
    asm volatile("s_waitcnt lgkmcnt(0)" ::: "memory");
    __builtin_amdgcn_s_setprio(1);
#pragma unroll
    for (int mi = 0; mi < 4; ++mi)
#pragma unroll
      for (int nj = 0; nj < 4; ++nj)
        acc[mi][nj] = __builtin_amdgcn_mfma_f32_16x16x32_bf16(a_[mi], b_[nj], acc[mi][nj], 0, 0, 0);
    __builtin_amdgcn_s_setprio(0);
    asm volatile("s_waitcnt vmcnt(0)" ::: "memory");
    __builtin_amdgcn_s_barrier();
  }

  // ---- epilogue ----
  const int rowt0 = ty * 128 + wm * 64;
  if (MODE == 0) {
    const int seg = tx >> 2;                       // 0:Q 1:K 2:V
    const int colseg0 = (tx & 3) * 256 + wn * 64;
    if (seg < 2) {
      short* Cb = (seg == 0) ? Qb : Kb;
      const float* bias = (seg == 0) ? bq : bk;
#pragma unroll
      for (int mf = 0; mf < 4; ++mf) {
#pragma unroll
        for (int nj = 0; nj < 4; ++nj) {
          int col = colseg0 + nj * 16 + r16;
          float bvv = bias[col];
#pragma unroll
          for (int rr = 0; rr < 4; ++rr) {
            int row = rowt0 + mf * 16 + kq * 4 + rr;
            Cb[(size_t)row * 1024 + col] = f2bf(acc[mf][nj][rr] + bvv);
          }
        }
      }
    } else {
      // Vt[b][e][n]
#pragma unroll
      for (int mf = 0; mf < 4; ++mf) {
        int rowg = rowt0 + mf * 16 + kq * 4;
        int b = rowg >> 11, n0 = rowg & 2047;
        long long base = (long long)b * (1024LL * 2048LL);
#pragma unroll
        for (int nj = 0; nj < 4; ++nj) {
          int col = colseg0 + nj * 16 + r16;
          float bvv = bv[col];
          bf16x4s o;
#pragma unroll
          for (int rr = 0; rr < 4; ++rr) o[rr] = f2bf(acc[mf][nj][rr] + bvv);
          *(bf16x4s*)&Vt[base + (long long)col * 2048 + n0] = o;
        }
      }
    }
  } else {
    short* Cb = Sb + bz * (2048LL * 2048LL);
    const int colt0 = tx * 256 + wn * 64;
#pragma unroll
    for (int mf = 0; mf < 4; ++mf) {
#pragma unroll
      for (int nj = 0; nj < 4; ++nj) {
        int col = colt0 + nj * 16 + r16;
#pragma unroll
        for (int rr = 0; rr < 4; ++rr) {
          int row = rowt0 + mf * 16 + kq * 4 + rr;
          float v = (col <= row) ? acc[mf][nj][rr] * scale : 0.0f;
          Cb[(size_t)row * 2048 + col] = f2bf(v);
        }
      }
    }
  }
}

// =================== 128x128 m97-style PV kernel ===================
#define BM 128
#define BN 128
#define BKK 32

__global__ __launch_bounds__(256) void gemm_pv(
    const short* __restrict__ S, const short* __restrict__ Vt,
    float* __restrict__ O) {
  const int tx = blockIdx.x, bz = blockIdx.z;
  const int ty = (int)gridDim.y - 1 - (int)blockIdx.y;  // longest-first
  const int Kend = (ty + 1) * BM;

  const short* Ab = S + (long long)bz * (2048LL * 2048LL);
  const short* Bb = Vt + (long long)bz * (1024LL * 2048LL);
  const int arow0 = ty * BM, brow0 = tx * BN;

  __shared__ short As[BM * BKK];
  __shared__ short Bs[BN * BKK];
  const int tid = threadIdx.x;
  const int wid = tid >> 6, lane = tid & 63;
  const int wm = wid >> 1, wn = wid & 1;
  const int kq = lane >> 4, r16 = lane & 15;
  const int srow = lane >> 2, scol = (lane & 3) * 8;
  f32x4 acc[4][4];
#pragma unroll
  for (int i = 0; i < 4; ++i)
#pragma unroll
    for (int j = 0; j < 4; ++j) { f32x4 z = {0.f, 0.f, 0.f, 0.f}; acc[i][j] = z; }

  for (int k0 = 0; k0 < Kend; k0 += BKK) {
    __syncthreads();
#pragma unroll
    for (int p = 0; p < 2; ++p) {
      int c = p * 4 + wid;
      const short* ga = Ab + ((size_t)(arow0 + c * 16 + srow)) * 2048 + k0 + scol;
      __builtin_amdgcn_global_load_lds(
          (const __attribute__((address_space(1))) void*)ga,
          (__attribute__((address_space(3))) void*)&As[c * 512], 16, 0, 0);
      const short* gb = Bb + ((size_t)(brow0 + c * 16 + srow)) * 2048 + k0 + scol;
      __builtin_amdgcn_global_load_lds(
          (const __attribute__((address_space(1))) void*)gb,
          (__attribute__((address_space(3))) void*)&Bs[c * 512], 16, 0, 0);
    }
    asm volatile("s_waitcnt vmcnt(0)" ::: "memory");
    __syncthreads();
    bf16x8s af[4], bfr[4];
#pragma unroll
    for (int i = 0; i < 4; ++i)
      af[i] = *(const bf16x8s*)&As[(wm * 64 + i * 16 + r16) * BKK + kq * 8];
#pragma unroll
    for (int j = 0; j < 4; ++j)
      bfr[j] = *(const bf16x8s*)&Bs[(wn * 64 + j * 16 + r16) * BKK + kq * 8];
#pragma unroll
    for (int i = 0; i < 4; ++i)
#pragma unroll
      for (int j = 0; j < 4; ++j)
        acc[i][j] = __builtin_amdgcn_mfma_f32_16x16x32_bf16(af[i], bfr[j], acc[i][j], 0, 0, 0);
  }

  float* Cb = O + (long long)bz * (2048LL * 1024LL);
  const int row0 = ty * BM + wm * 64;
  const int col0 = tx * BN + wn * 64;
#pragma unroll
  for (int i2 = 0; i2 < 4; ++i2) {
#pragma unroll
    for (int j = 0; j < 4; ++j) {
      int col = col0 + j * 16 + r16;
#pragma unroll
      for (int r = 0; r < 4; ++r) {
        int row = row0 + i2 * 16 + kq * 4 + r;
        Cb[(size_t)row * 1024 + col] = acc[i2][j][r];
      }
    }
  }
}

extern "C" void kernel_launch(void* const* d_in, const int* in_sizes, int n_in,
                              void* d_out, int out_size, void* d_ws, size_t ws_size,
                              hipStream_t stream) {
  const float* x  = (const float*)d_in[0];
  const float* Wq = (const float*)d_in[1];
  const float* bq = (const float*)d_in[2];
  const float* Wk = (const float*)d_in[3];
  const float* bk = (const float*)d_in[4];
  const float* Wv = (const float*)d_in[5];
  const float* bv = (const float*)d_in[6];

  const int B = 4;
  const long long MB = 1LL << 20;

  char* ws = (char*)d_ws;
  short* Qb   = (short*)(ws + 0 * MB);   // 16 MB bf16 Q [8192,1024]
  short* Kb   = (short*)(ws + 16 * MB);  // 16 MB bf16 K
  short* Vt   = (short*)(ws + 32 * MB);  // 16 MB bf16 V^T [4][1024][2048]
  short* xb   = (short*)(ws + 48 * MB);  // 16 MB bf16 x     (dead after QKV)
  short* Wcat = (short*)(ws + 64 * MB);  // 6 MB  bf16 [Wq;Wk;Wv] (dead after QKV)
  short* Sb   = (short*)(ws + 48 * MB);  // 32 MB scores, reuses xb/Wcat

  // 1. fused casts
  cast_all<<<2048, 256, 0, stream>>>(x, Wq, Wk, Wv, xb, Wcat);

  // 2. fused QKV projection: [8192,3072] = xb @ Wcat^T ; 768 blocks, 2+/CU
  gemm2p<0><<<768, 512, 0, stream>>>(xb, Wcat, bq, bk, bv, Qb, Kb, Vt, nullptr, 1.0f);

  // 3. scores: per batch S = tril(Q K^T) / 32, 72 (128x256) tiles x 4 batches
  dim3 g2(72, 1, B);
  gemm2p<2><<<g2, 512, 0, stream>>>(Qb, Kb, nullptr, nullptr, nullptr, nullptr,
                                    nullptr, nullptr, Sb, 0.03125f);

  // 4. PV: per batch O = S @ Vt^T, causal K-extent, longest-first
  dim3 g3(8, 16, B);
  gemm_pv<<<g3, 256, 0, stream>>>(Sb, Vt, (float*)d_out);
}

// Round 9
// 147.191 us; speedup vs baseline: 1.2401x; 1.1564x over previous
//
#include <hip/hip_runtime.h>
#include <hip/hip_bf16.h>
#include <stdint.h>

// out = tril(Q K^T) * scale @ V  (no softmax), Q/K/V = x @ W^T + b
// B=4, N=2048, D=1024, f32 in/out; bf16 MFMA, f32 accum.
// QKV / scores / PV: 128x256 tile, BK=32, depth-2 counted-vmcnt pipeline,
// triple-buffered 72 KiB LDS, 2 blocks/CU.

typedef __attribute__((ext_vector_type(4))) float f32x4;
typedef __attribute__((ext_vector_type(8))) short bf16x8s;
typedef __attribute__((ext_vector_type(4))) short bf16x4s;

__device__ __forceinline__ short f2bf(float f) {
  union { float f; unsigned u; } v; v.f = f;
  return (short)((v.u + 0x7FFFu + ((v.u >> 16) & 1u)) >> 16);  // RNE
}

// ---------------- fused cast f32 -> bf16 ----------------
__global__ void cast_all(const float* __restrict__ x, const float* __restrict__ wq,
                         const float* __restrict__ wk, const float* __restrict__ wv,
                         short* __restrict__ xb, short* __restrict__ wcat) {
  const int n4x = 1 << 21;
  const int n4w = 1 << 18;
  const int total = n4x + 3 * n4w;
  int idx = blockIdx.x * blockDim.x + threadIdx.x;
  int stride = gridDim.x * blockDim.x;
  for (int i = idx; i < total; i += stride) {
    f32x4 v;
    short* dst;
    if (i < n4x) {
      v = ((const f32x4*)x)[i];
      dst = xb + (size_t)i * 4;
    } else {
      int j = i - n4x;
      int sel = j >> 18, off = j & (n4w - 1);
      const float* src = (sel == 0) ? wq : (sel == 1) ? wk : wv;
      v = ((const f32x4*)src)[off];
      dst = wcat + (size_t)j * 4;
    }
    bf16x4s o;
    o[0] = f2bf(v[0]); o[1] = f2bf(v[1]); o[2] = f2bf(v[2]); o[3] = f2bf(v[3]);
    *(bf16x4s*)dst = o;
  }
}

// ---------------- staging / fragment-read machinery ----------------
// Swizzle: 16B-slot s = ks ^ ((row>>1)&3); inverse on global src, applied on ds_read.

// stage 256 rows x 32 cols (16KB): 2 gload_lds(16B)/thread, linear LDS dest
#define STAGE2(gp, ld_, kelem, slot)                                                  \
  {                                                                                   \
    const int ksrc_ = (((lane & 3) ^ ((lane >> 3) & 3)) << 3);                        \
    _Pragma("unroll") for (int e_ = 0; e_ < 2; ++e_) {                                \
      int row_ = e_ * 128 + wid * 16 + (lane >> 2);                                   \
      const short* src_ = (gp) + (size_t)row_ * (ld_) + (kelem) + ksrc_;              \
      __builtin_amdgcn_global_load_lds(                                               \
          (const __attribute__((address_space(1))) void*)src_,                        \
          (__attribute__((address_space(3))) void*)((slot) + e_ * 4096 + wid * 512),  \
          16, 0, 0);                                                                  \
    }                                                                                 \
  }

// stage 128 rows x 32 cols (8KB): 1 gload_lds(16B)/thread
#define STAGE1(gp, ld_, kelem, slot)                                                  \
  {                                                                                   \
    const int ksrc_ = (((lane & 3) ^ ((lane >> 3) & 3)) << 3);                        \
    int row_ = wid * 16 + (lane >> 2);                                                \
    const short* src_ = (gp) + (size_t)row_ * (ld_) + (kelem) + ksrc_;                \
    __builtin_amdgcn_global_load_lds(                                                 \
        (const __attribute__((address_space(1))) void*)src_,                          \
        (__attribute__((address_space(3))) void*)((slot) + wid * 512), 16, 0, 0);     \
  }

#define LDSF(slot, row) \
  (*(const bf16x8s*)&(slot)[(row) * 32 + ((kq ^ (((row) >> 1) & 3)) << 3)])

// ========== 128x256 / BK=32 / depth-2 counted-vmcnt pipelined GEMM ==========
// 512 threads = 8 waves (2m x 4n), 64x64 out/wave, acc[4][4].
// LDS: 3 x (A 4096 + B 8192 shorts) = 72 KiB -> 2 blocks/CU.
// Tile T: STAGE(T+2) -> ds_read(T) -> lgkm -> MFMA -> vmcnt(3) [T+1 landed] -> bar.
// Loads stay 2 tiles in flight; vmcnt(0) only at the tail (T = NT-2).

// MODE 0: QKV. A=xb[8192,1024], B=Wcat[3072,1024]; epilogue seg -> Qb/Kb/Vt.
// MODE 2: scores. per-batch triangular; epilogue mask+scale -> Sb (bf16).
// MODE 3: PV. A=Sb[2048,2048], B=Vt[1024,2048]; variable NT=(ty+1)*4; f32 -> O.
template <int MODE>
__global__ __launch_bounds__(512, 4) void gemm2p(
    const short* __restrict__ A, const short* __restrict__ Bm,
    const float* __restrict__ bq, const float* __restrict__ bk,
    const float* __restrict__ bv, short* __restrict__ Qb,
    short* __restrict__ Kb, short* __restrict__ Vt,
    short* __restrict__ Sb, float* __restrict__ O, float scale) {
  const int ld = (MODE == 3) ? 2048 : 1024;
  int tx, ty, NTv;
  const short *Abase, *Bbase;
  long long bz = 0;
  if (MODE == 0) {
    int id = blockIdx.x;                 // 768 blocks; XCD-bijective (768 = 8*96)
    int swz = (id & 7) * 96 + (id >> 3);
    tx = swz % 12; ty = swz / 12;        // ty: 128-row A tile, tx: 256-row B tile
    Abase = A; Bbase = Bm;
    NTv = 32;
  } else if (MODE == 2) {
    bz = blockIdx.z;
    int id = blockIdx.x;                 // 72 tiles (128q x 256k); 72 = 8*9
    int ti = (id & 7) * 9 + (id >> 3);
    int qt = 0, c = 0;
    while (c + (qt / 2 + 1) <= ti) { c += qt / 2 + 1; ++qt; }
    ty = qt; tx = ti - c;
    Abase = A + bz * (2048LL * 1024LL);
    Bbase = Bm + bz * (2048LL * 1024LL);
    NTv = 32;
  } else {
    bz = blockIdx.z;
    int id = blockIdx.x;                 // 64 tiles: 16 q-tiles x 4 e-tiles
    tx = id & 3;
    ty = 15 - (id >> 2);                 // longest-first
    Abase = A + bz * (2048LL * 2048LL);
    Bbase = Bm + bz * (1024LL * 2048LL);
    NTv = (ty + 1) * 4;                  // Kend = (ty+1)*128
  }
  const short* Ap = Abase + (size_t)(ty * 128) * ld;
  const short* Bp = Bbase + (size_t)(tx * 256) * ld;

  __shared__ short lds[36864];  // 72 KiB: A slots @ s*4096 (s<3), B @ 12288 + s*8192

  const int tid = threadIdx.x;
  const int wid = tid >> 6, lane = tid & 63;
  const int wm = wid >> 2, wn = wid & 3;   // 2 x 4 waves, 64x64 out each
  const int kq = lane >> 4, r16 = lane & 15;

  f32x4 acc[4][4];
#pragma unroll
  for (int i = 0; i < 4; ++i)
#pragma unroll
    for (int j = 0; j < 4; ++j) { f32x4 z = {0.f, 0.f, 0.f, 0.f}; acc[i][j] = z; }

  // prologue: stage tiles 0 and 1 (slots 0, 1); wait tile 0 (3 newest in flight)
  STAGE1(Ap, ld, 0, (lds + 0));
  STAGE2(Bp, ld, 0, (lds + 12288));
  STAGE1(Ap, ld, 32, (lds + 4096));
  STAGE2(Bp, ld, 32, (lds + 12288 + 8192));
  asm volatile("s_waitcnt vmcnt(3)" ::: "memory");
  __builtin_amdgcn_s_barrier();

  int cs = 0;  // slot of tile T
  for (int T = 0; T < NTv; ++T) {
    int ns = cs + 2; if (ns >= 3) ns -= 3;   // slot of tile T+2
    if (T + 2 < NTv) {
      STAGE1(Ap, ld, (T + 2) * 32, (lds + ns * 4096));
      STAGE2(Bp, ld, (T + 2) * 32, (lds + 12288 + ns * 8192));
    }
    short* curA = lds + cs * 4096;
    short* curB = lds + 12288 + cs * 8192;
    bf16x8s a_[4], b_[4];
#pragma unroll
    for (int mi = 0; mi < 4; ++mi)
      a_[mi] = LDSF(curA, wm * 64 + mi * 16 + r16);
#pragma unroll
    for (int nj = 0; nj < 4; ++nj)
      b_[nj] = LDSF(curB, wn * 64 + nj * 16 + r16);
    asm volatile("s_waitcnt lgkmcnt(0)" ::: "memory");
    __builtin_amdgcn_s_setprio(1);
#pragma unroll
    for (int mi = 0; mi < 4; ++mi)
#pragma unroll
      for (int nj = 0; nj < 4; ++nj)
        acc[mi][nj] = __builtin_amdgcn_mfma_f32_16x16x32_bf16(a_[mi], b_[nj], acc[mi][nj], 0, 0, 0);
    __builtin_amdgcn_s_setprio(0);
    if (T < NTv - 2) {
      asm volatile("s_waitcnt vmcnt(3)" ::: "memory");  // tile T+1 landed
    } else {
      asm volatile("s_waitcnt vmcnt(0)" ::: "memory");  // tail drain
    }
    __builtin_amdgcn_s_barrier();
    cs = (cs + 1 == 3) ? 0 : cs + 1;
  }

  // ---- epilogue ----
  const int rowt0 = ty * 128 + wm * 64;
  if (MODE == 0) {
    const int seg = tx >> 2;                       // 0:Q 1:K 2:V
    const int colseg0 = (tx & 3) * 256 + wn * 64;
    if (seg < 2) {
      short* Cb = (seg == 0) ? Qb : Kb;
      const float* bias = (seg == 0) ? bq : bk;
#pragma unroll
      for (int mf = 0; mf < 4; ++mf) {
#pragma unroll
        for (int nj = 0; nj < 4; ++nj) {
          int col = colseg0 + nj * 16 + r16;
          float bvv = bias[col];
#pragma unroll
          for (int rr = 0; rr < 4; ++rr) {
            int row = rowt0 + mf * 16 + kq * 4 + rr;
            Cb[(size_t)row * 1024 + col] = f2bf(acc[mf][nj][rr] + bvv);
          }
        }
      }
    } else {
      // Vt[b][e][n]
#pragma unroll
      for (int mf = 0; mf < 4; ++mf) {
        int rowg = rowt0 + mf * 16 + kq * 4;
        int b = rowg >> 11, n0 = rowg & 2047;
        long long base = (long long)b * (1024LL * 2048LL);
#pragma unroll
        for (int nj = 0; nj < 4; ++nj) {
          int col = colseg0 + nj * 16 + r16;
          float bvv = bv[col];
          bf16x4s o;
#pragma unroll
          for (int rr = 0; rr < 4; ++rr) o[rr] = f2bf(acc[mf][nj][rr] + bvv);
          *(bf16x4s*)&Vt[base + (long long)col * 2048 + n0] = o;
        }
      }
    }
  } else if (MODE == 2) {
    short* Cb = Sb + bz * (2048LL * 2048LL);
    const int colt0 = tx * 256 + wn * 64;
#pragma unroll
    for (int mf = 0; mf < 4; ++mf) {
#pragma unroll
      for (int nj = 0; nj < 4; ++nj) {
        int col = colt0 + nj * 16 + r16;
#pragma unroll
        for (int rr = 0; rr < 4; ++rr) {
          int row = rowt0 + mf * 16 + kq * 4 + rr;
          float v = (col <= row) ? acc[mf][nj][rr] * scale : 0.0f;
          Cb[(size_t)row * 2048 + col] = f2bf(v);
        }
      }
    }
  } else {
    float* Cb = O + bz * (2048LL * 1024LL);
    const int colt0 = tx * 256 + wn * 64;
#pragma unroll
    for (int mf = 0; mf < 4; ++mf) {
#pragma unroll
      for (int nj = 0; nj < 4; ++nj) {
        int col = colt0 + nj * 16 + r16;
#pragma unroll
        for (int rr = 0; rr < 4; ++rr) {
          int row = rowt0 + mf * 16 + kq * 4 + rr;
          Cb[(size_t)row * 1024 + col] = acc[mf][nj][rr];
        }
      }
    }
  }
}

extern "C" void kernel_launch(void* const* d_in, const int* in_sizes, int n_in,
                              void* d_out, int out_size, void* d_ws, size_t ws_size,
                              hipStream_t stream) {
  const float* x  = (const float*)d_in[0];
  const float* Wq = (const float*)d_in[1];
  const float* bq = (const float*)d_in[2];
  const float* Wk = (const float*)d_in[3];
  const float* bk = (const float*)d_in[4];
  const float* Wv = (const float*)d_in[5];
  const float* bv = (const float*)d_in[6];

  const int B = 4;
  const long long MB = 1LL << 20;

  char* ws = (char*)d_ws;
  short* Qb   = (short*)(ws + 0 * MB);   // 16 MB bf16 Q [8192,1024]
  short* Kb   = (short*)(ws + 16 * MB);  // 16 MB bf16 K
  short* Vt   = (short*)(ws + 32 * MB);  // 16 MB bf16 V^T [4][1024][2048]
  short* xb   = (short*)(ws + 48 * MB);  // 16 MB bf16 x     (dead after QKV)
  short* Wcat = (short*)(ws + 64 * MB);  // 6 MB  bf16 [Wq;Wk;Wv] (dead after QKV)
  short* Sb   = (short*)(ws + 48 * MB);  // 32 MB scores, reuses xb/Wcat

  // 1. fused casts
  cast_all<<<2048, 256, 0, stream>>>(x, Wq, Wk, Wv, xb, Wcat);

  // 2. fused QKV projection: [8192,3072] = xb @ Wcat^T ; 768 blocks
  gemm2p<0><<<768, 512, 0, stream>>>(xb, Wcat, bq, bk, bv, Qb, Kb, Vt,
                                     nullptr, nullptr, 1.0f);

  // 3. scores: per batch S = tril(Q K^T) / 32, 72 (128x256) tiles x 4 batches
  dim3 g2(72, 1, B);
  gemm2p<2><<<g2, 512, 0, stream>>>(Qb, Kb, nullptr, nullptr, nullptr, nullptr,
                                    nullptr, nullptr, Sb, nullptr, 0.03125f);

  // 4. PV: per batch O = S @ Vt^T, causal K-extent, longest-first
  dim3 g3(64, 1, B);
  gemm2p<3><<<g3, 512, 0, stream>>>(Sb, Vt, nullptr, nullptr, nullptr, nullptr,
                                    nullptr, nullptr, nullptr, (float*)d_out, 1.0f);
}